// Round 6
// baseline (278.386 us; speedup 1.0000x reference)
//
#include <hip/hip_runtime.h>
#include <hip/hip_bf16.h>

#define NNODES 12288
#define NEDGES (NNODES * 32)
#define ELLCAP 128  // max degree ~56 expected (Binomial tail); 128 unreachable

typedef __attribute__((ext_vector_type(4))) float f32x4;
typedef __attribute__((ext_vector_type(8))) __bf16 bf16x8;

// ---------------- fused prep: zero deg + 3 weight transpose-casts ----------------
__global__ __launch_bounds__(256) void prep_kernel(const float* __restrict__ W1,
                                                   const float* __restrict__ W2,
                                                   const float* __restrict__ W3,
                                                   __bf16* __restrict__ W1t,
                                                   __bf16* __restrict__ W2t,
                                                   __bf16* __restrict__ W3t,
                                                   int* __restrict__ deg) {
    int i = blockIdx.x * 256 + threadIdx.x;
    if (i < NNODES) { deg[i] = 0; return; }
    int j = i - NNODES;
    if (j < 512 * 256) { W1t[(size_t)(j % 256) * 512 + j / 256] = (__bf16)W1[j]; return; }
    j -= 512 * 256;
    if (j < 256 * 128) { W2t[(size_t)(j % 128) * 256 + j / 128] = (__bf16)W2[j]; return; }
    j -= 256 * 128;
    if (j < 128 * 64) { W3t[(size_t)(j % 64) * 128 + j / 64] = (__bf16)W3[j]; return; }
}

// ---------------- ELL build: one pass, no scan ----------------
__global__ __launch_bounds__(256) void scatter_ell(const int* __restrict__ row,
                                                   const int* __restrict__ col,
                                                   const float* __restrict__ w,
                                                   int* __restrict__ deg,
                                                   int2* __restrict__ ell) {
    int e = blockIdx.x * 256 + threadIdx.x;
    int r = row[e];
    int p = atomicAdd(&deg[r], 1);
    int2 cw; cw.x = col[e]; cw.y = __float_as_int(w[e]);
    ell[(size_t)r * ELLCAP + p] = cw;
}

// ---------------- layer-1 GEMM: bf16 MFMA 16x16x32, f32 A cast in-register ----------------
// Grid (M/128, Nc/64): m on blockIdx.x so A-panel sharers differ by 96 (%8==0 -> same XCD L2).
template <bool TANH, int K, bool A_F32>
__global__ __launch_bounds__(256) void gemm_mfma(const void* __restrict__ Av,
                                                 const __bf16* __restrict__ Wt,
                                                 __bf16* __restrict__ C, int Nc) {
    int wave = threadIdx.x >> 6, lane = threadIdx.x & 63;
    int lr = lane & 15;
    int kg = lane >> 4;
    int m0 = blockIdx.x * 128 + wave * 32;
    int n0 = blockIdx.y * 64;
    f32x4 acc[2][4];
#pragma unroll
    for (int mi = 0; mi < 2; mi++)
#pragma unroll
        for (int ni = 0; ni < 4; ni++) acc[mi][ni] = (f32x4){0.f, 0.f, 0.f, 0.f};
#pragma unroll
    for (int k0 = 0; k0 < K; k0 += 32) {
        bf16x8 af[2], bf[4];
#pragma unroll
        for (int mi = 0; mi < 2; mi++) {
            if (A_F32) {
                const float* ap = (const float*)Av + (size_t)(m0 + mi * 16 + lr) * K + k0 + kg * 8;
                f32x4 a0 = *(const f32x4*)ap;
                f32x4 a1 = *(const f32x4*)(ap + 4);
#pragma unroll
                for (int j = 0; j < 4; j++) { af[mi][j] = (__bf16)a0[j]; af[mi][4 + j] = (__bf16)a1[j]; }
            } else {
                af[mi] = *(const bf16x8*)((const __bf16*)Av + (size_t)(m0 + mi * 16 + lr) * K + k0 + kg * 8);
            }
        }
#pragma unroll
        for (int ni = 0; ni < 4; ni++)
            bf[ni] = *(const bf16x8*)(Wt + (size_t)(n0 + ni * 16 + lr) * K + k0 + kg * 8);
#pragma unroll
        for (int mi = 0; mi < 2; mi++)
#pragma unroll
            for (int ni = 0; ni < 4; ni++)
                acc[mi][ni] = __builtin_amdgcn_mfma_f32_16x16x32_bf16(af[mi], bf[ni], acc[mi][ni], 0, 0, 0);
    }
    // C/D layout (m89-verified): col = lane&15, row = (lane>>4)*4 + reg
#pragma unroll
    for (int mi = 0; mi < 2; mi++)
#pragma unroll
        for (int ni = 0; ni < 4; ni++) {
            int col = n0 + ni * 16 + lr;
            int rowb = m0 + mi * 16 + kg * 4;
#pragma unroll
            for (int r = 0; r < 4; r++) {
                float v = acc[mi][ni][r];
                if (TANH) v = tanhf(v);
                C[(size_t)(rowb + r) * Nc + col] = (__bf16)v;
            }
        }
}

// ---------------- fused: z = spmm(h_in) then h_out = act(z @ W) ----------------
template <int K, int NOUT, bool TANH>
__global__ __launch_bounds__(16 * K / 8) void fused_spmm_gemm(const int* __restrict__ deg,
                                                              const int2* __restrict__ ell,
                                                              const __bf16* __restrict__ h_in,
                                                              const __bf16* __restrict__ Wt,
                                                              __bf16* __restrict__ h_out) {
    constexpr int L = K / 8;  // lanes per row in phase A
    __shared__ __bf16 zs[16][K + 4];
    int tid = threadIdx.x;
    int rloc = tid / L;
    int f8 = (tid % L) * 8;
    int rglob = blockIdx.x * 16 + rloc;
    int d = deg[rglob];
    const int2* er = ell + (size_t)rglob * ELLCAP;
    float acc[8] = {};
#pragma unroll 8
    for (int e = 0; e < d; e++) {
        int2 cw = er[e];
        float w = __int_as_float(cw.y);
        bf16x8 hv = *(const bf16x8*)(h_in + (size_t)cw.x * K + f8);
#pragma unroll
        for (int j = 0; j < 8; j++) acc[j] = fmaf(w, (float)hv[j], acc[j]);
    }
    bf16x8 o;
#pragma unroll
    for (int j = 0; j < 8; j++) o[j] = (__bf16)acc[j];
    *(bf16x8*)&zs[rloc][f8] = o;
    __syncthreads();
    // phase B: wave w computes out cols [w*16, w*16+16), rows = block's 16
    int wave = tid >> 6, lane = tid & 63;
    int lr = lane & 15, kg = lane >> 4;
    f32x4 c = (f32x4){0.f, 0.f, 0.f, 0.f};
#pragma unroll
    for (int ks = 0; ks < K / 32; ks++) {
        bf16x8 a = *(const bf16x8*)&zs[lr][ks * 32 + kg * 8];
        bf16x8 b = *(const bf16x8*)(Wt + (size_t)(wave * 16 + lr) * K + ks * 32 + kg * 8);
        c = __builtin_amdgcn_mfma_f32_16x16x32_bf16(a, b, c, 0, 0, 0);
    }
#pragma unroll
    for (int r = 0; r < 4; r++) {
        float v = c[r];
        if (TANH) v = tanhf(v);
        h_out[(size_t)(blockIdx.x * 16 + kg * 4 + r) * NOUT + wave * 16 + lr] = (__bf16)v;
    }
}

// ---------------- final SpMM (F=64): writes Zb bf16 + z_igae f32 ----------------
__global__ __launch_bounds__(256) void spmm_final(const int* __restrict__ deg,
                                                  const int2* __restrict__ ell,
                                                  const __bf16* __restrict__ h,
                                                  __bf16* __restrict__ z,
                                                  float* __restrict__ zf) {
    int r = blockIdx.x * 32 + threadIdx.x / 8;
    int f8 = (threadIdx.x & 7) * 8;
    int d = deg[r];
    const int2* er = ell + (size_t)r * ELLCAP;
    float acc[8] = {};
#pragma unroll 8
    for (int e = 0; e < d; e++) {
        int2 cw = er[e];
        float w = __int_as_float(cw.y);
        bf16x8 hv = *(const bf16x8*)(h + (size_t)cw.x * 64 + f8);
#pragma unroll
        for (int j = 0; j < 8; j++) acc[j] = fmaf(w, (float)hv[j], acc[j]);
    }
    bf16x8 o;
#pragma unroll
    for (int j = 0; j < 8; j++) o[j] = (__bf16)acc[j];
    *(bf16x8*)(z + (size_t)r * 64 + f8) = o;
    f32x4 o0, o1;
#pragma unroll
    for (int j = 0; j < 4; j++) { o0[j] = acc[j]; o1[j] = acc[4 + j]; }
    *(f32x4*)(zf + (size_t)r * 64 + f8) = o0;
    *(f32x4*)(zf + (size_t)r * 64 + f8 + 4) = o1;
}

// ---------------- adj = sigmoid(Z Z^T), Z bf16 [N,64], MFMA 16x16x32 ----------------
// Epilogue: TRANSPOSED-SYMMETRIC stores. zz^T is symmetric and sigmoid is
// elementwise, so fragment value V[i][j] (i = a-side row, j = b-side row) can be
// written to out[(c0+j)*N + (r0+i)]. In that orientation the 4 accumulator regs
// (i = kg*4+r) are 4 CONSECUTIVE addresses -> one global_store_dwordx4 per
// fragment: 16 stores/lane instead of 64 scalar stores.
__global__ __launch_bounds__(256) void zzt_sigmoid(const __bf16* __restrict__ Z,
                                                   float* __restrict__ out) {
    int wave = threadIdx.x >> 6;
    int lane = threadIdx.x & 63;
    int lr = lane & 15;
    int kg = lane >> 4;
    int r0 = blockIdx.y * 64;
    int c0 = blockIdx.x * 256 + wave * 64;
    bf16x8 af[4][2], bfr[4][2];
#pragma unroll
    for (int i = 0; i < 4; i++)
#pragma unroll
        for (int ks = 0; ks < 2; ks++) {
            af[i][ks]  = *(const bf16x8*)(Z + (size_t)(r0 + i * 16 + lr) * 64 + ks * 32 + kg * 8);
            bfr[i][ks] = *(const bf16x8*)(Z + (size_t)(c0 + i * 16 + lr) * 64 + ks * 32 + kg * 8);
        }
    f32x4 acc[4][4];
#pragma unroll
    for (int mi = 0; mi < 4; mi++)
#pragma unroll
        for (int ni = 0; ni < 4; ni++) acc[mi][ni] = (f32x4){0.f, 0.f, 0.f, 0.f};
#pragma unroll
    for (int mi = 0; mi < 4; mi++)
#pragma unroll
        for (int ni = 0; ni < 4; ni++) {
            acc[mi][ni] = __builtin_amdgcn_mfma_f32_16x16x32_bf16(af[mi][0], bfr[ni][0], acc[mi][ni], 0, 0, 0);
            acc[mi][ni] = __builtin_amdgcn_mfma_f32_16x16x32_bf16(af[mi][1], bfr[ni][1], acc[mi][ni], 0, 0, 0);
        }
#pragma unroll
    for (int mi = 0; mi < 4; mi++)
#pragma unroll
        for (int ni = 0; ni < 4; ni++) {
            int orow = c0 + ni * 16 + lr;        // b-side index -> output row (transposed)
            int ocol = r0 + mi * 16 + kg * 4;    // a-side index -> output col, 16B aligned
            f32x4 v;
#pragma unroll
            for (int r = 0; r < 4; r++) {
                float e = __expf(-acc[mi][ni][r]);
                v[r] = __builtin_amdgcn_rcpf(1.f + e);
            }
            *(f32x4*)(out + (size_t)orow * NNODES + ocol) = v;
        }
}

extern "C" void kernel_launch(void* const* d_in, const int* in_sizes, int n_in,
                              void* d_out, int out_size, void* d_ws, size_t ws_size,
                              hipStream_t stream) {
    (void)in_sizes; (void)n_in; (void)out_size; (void)ws_size;
    const float* x  = (const float*)d_in[0];
    const int* erow = (const int*)d_in[1];
    const int* ecol = (const int*)d_in[2];
    const float* ew = (const float*)d_in[3];
    const float* W1 = (const float*)d_in[4];
    const float* W2 = (const float*)d_in[5];
    const float* W3 = (const float*)d_in[6];
    float* z_igae = (float*)d_out;
    float* adj = (float*)d_out + (size_t)NNODES * 64;

    char* ws = (char*)d_ws;
    size_t off = 0;
    auto alloc = [&](size_t bytes) {
        void* p = ws + off;
        off += (bytes + 255) & ~(size_t)255;
        return p;
    };
    __bf16* W1t = (__bf16*)alloc((size_t)512 * 256 * 2);
    __bf16* W2t = (__bf16*)alloc((size_t)256 * 128 * 2);
    __bf16* W3t = (__bf16*)alloc((size_t)128 * 64 * 2);
    __bf16* h1  = (__bf16*)alloc((size_t)NNODES * 256 * 2);
    __bf16* h2  = (__bf16*)alloc((size_t)NNODES * 128 * 2);
    __bf16* h3  = (__bf16*)alloc((size_t)NNODES * 64 * 2);
    __bf16* Zb  = (__bf16*)alloc((size_t)NNODES * 64 * 2);
    int* deg    = (int*)alloc(NNODES * 4);
    int2* ell   = (int2*)alloc((size_t)NNODES * ELLCAP * 8);

    // prep (zero deg + weight casts), then ELL build
    prep_kernel<<<(NNODES + 512 * 256 + 256 * 128 + 128 * 64 + 255) / 256, 256, 0, stream>>>(
        W1, W2, W3, W1t, W2t, W3t, deg);
    scatter_ell<<<NEDGES / 256, 256, 0, stream>>>(erow, ecol, ew, deg, ell);

    // layer 1: h1 = tanh(x @ W1)  (f32 A cast in-register)
    gemm_mfma<true, 512, true><<<dim3(NNODES / 128, 256 / 64), 256, 0, stream>>>(x, W1t, h1, 256);
    // fused layer 1->2: z1 = spmm(h1); h2 = tanh(z1 @ W2)   [512 thr, 8 waves]
    fused_spmm_gemm<256, 128, true><<<NNODES / 16, 512, 0, stream>>>(deg, ell, h1, W2t, h2);
    // fused layer 2->3: z2 = spmm(h2); h3 = z2 @ W3         [256 thr, 4 waves]
    fused_spmm_gemm<128, 64, false><<<NNODES / 16, 256, 0, stream>>>(deg, ell, h2, W3t, h3);
    // final spmm: z_igae = spmm(h3) (f32 out + bf16 copy for zzt)
    spmm_final<<<NNODES / 32, 256, 0, stream>>>(deg, ell, h3, Zb, z_igae);
    // adjacency reconstruction
    zzt_sigmoid<<<dim3(NNODES / 256, NNODES / 64), 256, 0, stream>>>((const __bf16*)Zb, adj);
}

// Round 7
// 234.487 us; speedup vs baseline: 1.1872x; 1.1872x over previous
//
#include <hip/hip_runtime.h>
#include <hip/hip_bf16.h>

#define NNODES 12288
#define NEDGES (NNODES * 32)
#define ELLCAP 128  // max degree ~56 expected (Binomial tail); 128 unreachable

typedef __attribute__((ext_vector_type(4))) float f32x4;
typedef __attribute__((ext_vector_type(8))) __bf16 bf16x8;

// ---------------- fused prep: zero deg + 3 weight transpose-casts ----------------
__global__ __launch_bounds__(256) void prep_kernel(const float* __restrict__ W1,
                                                   const float* __restrict__ W2,
                                                   const float* __restrict__ W3,
                                                   __bf16* __restrict__ W1t,
                                                   __bf16* __restrict__ W2t,
                                                   __bf16* __restrict__ W3t,
                                                   int* __restrict__ deg) {
    int i = blockIdx.x * 256 + threadIdx.x;
    if (i < NNODES) { deg[i] = 0; return; }
    int j = i - NNODES;
    if (j < 512 * 256) { W1t[(size_t)(j % 256) * 512 + j / 256] = (__bf16)W1[j]; return; }
    j -= 512 * 256;
    if (j < 256 * 128) { W2t[(size_t)(j % 128) * 256 + j / 128] = (__bf16)W2[j]; return; }
    j -= 256 * 128;
    if (j < 128 * 64) { W3t[(size_t)(j % 64) * 128 + j / 64] = (__bf16)W3[j]; return; }
}

// ---------------- ELL build: one pass, no scan ----------------
__global__ __launch_bounds__(256) void scatter_ell(const int* __restrict__ row,
                                                   const int* __restrict__ col,
                                                   const float* __restrict__ w,
                                                   int* __restrict__ deg,
                                                   int2* __restrict__ ell) {
    int e = blockIdx.x * 256 + threadIdx.x;
    int r = row[e];
    int p = atomicAdd(&deg[r], 1);
    int2 cw; cw.x = col[e]; cw.y = __float_as_int(w[e]);
    ell[(size_t)r * ELLCAP + p] = cw;
}

// ---------------- layer-1 GEMM: bf16 MFMA 16x16x32, f32 A cast in-register ----------------
template <bool TANH, int K, bool A_F32>
__global__ __launch_bounds__(256) void gemm_mfma(const void* __restrict__ Av,
                                                 const __bf16* __restrict__ Wt,
                                                 __bf16* __restrict__ C, int Nc) {
    int wave = threadIdx.x >> 6, lane = threadIdx.x & 63;
    int lr = lane & 15;
    int kg = lane >> 4;
    int m0 = blockIdx.x * 128 + wave * 32;
    int n0 = blockIdx.y * 64;
    f32x4 acc[2][4];
#pragma unroll
    for (int mi = 0; mi < 2; mi++)
#pragma unroll
        for (int ni = 0; ni < 4; ni++) acc[mi][ni] = (f32x4){0.f, 0.f, 0.f, 0.f};
#pragma unroll
    for (int k0 = 0; k0 < K; k0 += 32) {
        bf16x8 af[2], bf[4];
#pragma unroll
        for (int mi = 0; mi < 2; mi++) {
            if (A_F32) {
                const float* ap = (const float*)Av + (size_t)(m0 + mi * 16 + lr) * K + k0 + kg * 8;
                f32x4 a0 = *(const f32x4*)ap;
                f32x4 a1 = *(const f32x4*)(ap + 4);
#pragma unroll
                for (int j = 0; j < 4; j++) { af[mi][j] = (__bf16)a0[j]; af[mi][4 + j] = (__bf16)a1[j]; }
            } else {
                af[mi] = *(const bf16x8*)((const __bf16*)Av + (size_t)(m0 + mi * 16 + lr) * K + k0 + kg * 8);
            }
        }
#pragma unroll
        for (int ni = 0; ni < 4; ni++)
            bf[ni] = *(const bf16x8*)(Wt + (size_t)(n0 + ni * 16 + lr) * K + k0 + kg * 8);
#pragma unroll
        for (int mi = 0; mi < 2; mi++)
#pragma unroll
            for (int ni = 0; ni < 4; ni++)
                acc[mi][ni] = __builtin_amdgcn_mfma_f32_16x16x32_bf16(af[mi], bf[ni], acc[mi][ni], 0, 0, 0);
    }
    // C/D layout (m89-verified): col = lane&15, row = (lane>>4)*4 + reg
#pragma unroll
    for (int mi = 0; mi < 2; mi++)
#pragma unroll
        for (int ni = 0; ni < 4; ni++) {
            int col = n0 + ni * 16 + lr;
            int rowb = m0 + mi * 16 + kg * 4;
#pragma unroll
            for (int r = 0; r < 4; r++) {
                float v = acc[mi][ni][r];
                if (TANH) v = tanhf(v);
                C[(size_t)(rowb + r) * Nc + col] = (__bf16)v;
            }
        }
}

// ---------------- fused: z = spmm(h_in) then h_out = act(z @ W) ----------------
template <int K, int NOUT, bool TANH>
__global__ __launch_bounds__(16 * K / 8) void fused_spmm_gemm(const int* __restrict__ deg,
                                                              const int2* __restrict__ ell,
                                                              const __bf16* __restrict__ h_in,
                                                              const __bf16* __restrict__ Wt,
                                                              __bf16* __restrict__ h_out) {
    constexpr int L = K / 8;  // lanes per row in phase A
    __shared__ __bf16 zs[16][K + 4];
    int tid = threadIdx.x;
    int rloc = tid / L;
    int f8 = (tid % L) * 8;
    int rglob = blockIdx.x * 16 + rloc;
    int d = deg[rglob];
    const int2* er = ell + (size_t)rglob * ELLCAP;
    float acc[8] = {};
#pragma unroll 8
    for (int e = 0; e < d; e++) {
        int2 cw = er[e];
        float w = __int_as_float(cw.y);
        bf16x8 hv = *(const bf16x8*)(h_in + (size_t)cw.x * K + f8);
#pragma unroll
        for (int j = 0; j < 8; j++) acc[j] = fmaf(w, (float)hv[j], acc[j]);
    }
    bf16x8 o;
#pragma unroll
    for (int j = 0; j < 8; j++) o[j] = (__bf16)acc[j];
    *(bf16x8*)&zs[rloc][f8] = o;
    __syncthreads();
    // phase B: wave w computes out cols [w*16, w*16+16), rows = block's 16
    int wave = tid >> 6, lane = tid & 63;
    int lr = lane & 15, kg = lane >> 4;
    f32x4 c = (f32x4){0.f, 0.f, 0.f, 0.f};
#pragma unroll
    for (int ks = 0; ks < K / 32; ks++) {
        bf16x8 a = *(const bf16x8*)&zs[lr][ks * 32 + kg * 8];
        bf16x8 b = *(const bf16x8*)(Wt + (size_t)(wave * 16 + lr) * K + ks * 32 + kg * 8);
        c = __builtin_amdgcn_mfma_f32_16x16x32_bf16(a, b, c, 0, 0, 0);
    }
#pragma unroll
    for (int r = 0; r < 4; r++) {
        float v = c[r];
        if (TANH) v = tanhf(v);
        h_out[(size_t)(blockIdx.x * 16 + kg * 4 + r) * NOUT + wave * 16 + lr] = (__bf16)v;
    }
}

// ---------------- final SpMM (F=64): writes Zb bf16 + z_igae f32 ----------------
__global__ __launch_bounds__(256) void spmm_final(const int* __restrict__ deg,
                                                  const int2* __restrict__ ell,
                                                  const __bf16* __restrict__ h,
                                                  __bf16* __restrict__ z,
                                                  float* __restrict__ zf) {
    int r = blockIdx.x * 32 + threadIdx.x / 8;
    int f8 = (threadIdx.x & 7) * 8;
    int d = deg[r];
    const int2* er = ell + (size_t)r * ELLCAP;
    float acc[8] = {};
#pragma unroll 8
    for (int e = 0; e < d; e++) {
        int2 cw = er[e];
        float w = __int_as_float(cw.y);
        bf16x8 hv = *(const bf16x8*)(h + (size_t)cw.x * 64 + f8);
#pragma unroll
        for (int j = 0; j < 8; j++) acc[j] = fmaf(w, (float)hv[j], acc[j]);
    }
    bf16x8 o;
#pragma unroll
    for (int j = 0; j < 8; j++) o[j] = (__bf16)acc[j];
    *(bf16x8*)(z + (size_t)r * 64 + f8) = o;
    f32x4 o0, o1;
#pragma unroll
    for (int j = 0; j < 4; j++) { o0[j] = acc[j]; o1[j] = acc[4 + j]; }
    *(f32x4*)(zf + (size_t)r * 64 + f8) = o0;
    *(f32x4*)(zf + (size_t)r * 64 + f8 + 4) = o1;
}

// ---------------- adj = sigmoid(Z Z^T) with LDS-staged row-coalesced stores ----------------
// MFMA identical to round-5. Epilogue: stage 32 rows of the 64x256 f32 tile in
// LDS (2 phases), then each wave stores ONE FULL 1KB ROW per instruction
// (64 lanes x f32x4 contiguous) - the fill-kernel pattern proven at 6.7 TB/s.
// Stage-write LDS conflicts: exactly 2-way (free). Coop-read: full-BW b128 pattern.
__global__ __launch_bounds__(256) void zzt_sigmoid(const __bf16* __restrict__ Z,
                                                   float* __restrict__ out) {
    __shared__ float tile[32][260];  // 33.3 KB
    int wave = threadIdx.x >> 6;
    int lane = threadIdx.x & 63;
    int lr = lane & 15;
    int kg = lane >> 4;
    int r0 = blockIdx.y * 64;
    int c0blk = blockIdx.x * 256;
    int c0 = c0blk + wave * 64;
    bf16x8 af[4][2], bfr[4][2];
#pragma unroll
    for (int i = 0; i < 4; i++)
#pragma unroll
        for (int ks = 0; ks < 2; ks++) {
            af[i][ks]  = *(const bf16x8*)(Z + (size_t)(r0 + i * 16 + lr) * 64 + ks * 32 + kg * 8);
            bfr[i][ks] = *(const bf16x8*)(Z + (size_t)(c0 + i * 16 + lr) * 64 + ks * 32 + kg * 8);
        }
    f32x4 acc[4][4];
#pragma unroll
    for (int mi = 0; mi < 4; mi++)
#pragma unroll
        for (int ni = 0; ni < 4; ni++) acc[mi][ni] = (f32x4){0.f, 0.f, 0.f, 0.f};
#pragma unroll
    for (int mi = 0; mi < 4; mi++)
#pragma unroll
        for (int ni = 0; ni < 4; ni++) {
            acc[mi][ni] = __builtin_amdgcn_mfma_f32_16x16x32_bf16(af[mi][0], bfr[ni][0], acc[mi][ni], 0, 0, 0);
            acc[mi][ni] = __builtin_amdgcn_mfma_f32_16x16x32_bf16(af[mi][1], bfr[ni][1], acc[mi][ni], 0, 0, 0);
        }
    // epilogue: two 32-row phases
#pragma unroll
    for (int ph = 0; ph < 2; ph++) {
#pragma unroll
        for (int mi2 = 0; mi2 < 2; mi2++) {
            int mi = ph * 2 + mi2;
#pragma unroll
            for (int ni = 0; ni < 4; ni++) {
                int colb = wave * 64 + ni * 16 + lr;   // col within 256-block
                int rowl = mi2 * 16 + kg * 4;          // row within 32-row phase
#pragma unroll
                for (int r = 0; r < 4; r++) {
                    float e = __expf(-acc[mi][ni][r]);
                    tile[rowl + r][colb] = __builtin_amdgcn_rcpf(1.f + e);
                }
            }
        }
        __syncthreads();
        // cooperative store: wave writes rows (it*4 + wave); one full row per instr
#pragma unroll
        for (int it = 0; it < 8; it++) {
            int rowl = it * 4 + wave;
            size_t grow = (size_t)(r0 + ph * 32 + rowl);
            *(f32x4*)(out + grow * NNODES + c0blk + lane * 4) = *(const f32x4*)&tile[rowl][lane * 4];
        }
        __syncthreads();
    }
}

extern "C" void kernel_launch(void* const* d_in, const int* in_sizes, int n_in,
                              void* d_out, int out_size, void* d_ws, size_t ws_size,
                              hipStream_t stream) {
    (void)in_sizes; (void)n_in; (void)out_size; (void)ws_size;
    const float* x  = (const float*)d_in[0];
    const int* erow = (const int*)d_in[1];
    const int* ecol = (const int*)d_in[2];
    const float* ew = (const float*)d_in[3];
    const float* W1 = (const float*)d_in[4];
    const float* W2 = (const float*)d_in[5];
    const float* W3 = (const float*)d_in[6];
    float* z_igae = (float*)d_out;
    float* adj = (float*)d_out + (size_t)NNODES * 64;

    char* ws = (char*)d_ws;
    size_t off = 0;
    auto alloc = [&](size_t bytes) {
        void* p = ws + off;
        off += (bytes + 255) & ~(size_t)255;
        return p;
    };
    __bf16* W1t = (__bf16*)alloc((size_t)512 * 256 * 2);
    __bf16* W2t = (__bf16*)alloc((size_t)256 * 128 * 2);
    __bf16* W3t = (__bf16*)alloc((size_t)128 * 64 * 2);
    __bf16* h1  = (__bf16*)alloc((size_t)NNODES * 256 * 2);
    __bf16* h2  = (__bf16*)alloc((size_t)NNODES * 128 * 2);
    __bf16* h3  = (__bf16*)alloc((size_t)NNODES * 64 * 2);
    __bf16* Zb  = (__bf16*)alloc((size_t)NNODES * 64 * 2);
    int* deg    = (int*)alloc(NNODES * 4);
    int2* ell   = (int2*)alloc((size_t)NNODES * ELLCAP * 8);

    // prep (zero deg + weight casts), then ELL build
    prep_kernel<<<(NNODES + 512 * 256 + 256 * 128 + 128 * 64 + 255) / 256, 256, 0, stream>>>(
        W1, W2, W3, W1t, W2t, W3t, deg);
    scatter_ell<<<NEDGES / 256, 256, 0, stream>>>(erow, ecol, ew, deg, ell);

    // layer 1: h1 = tanh(x @ W1)  (f32 A cast in-register)
    gemm_mfma<true, 512, true><<<dim3(NNODES / 128, 256 / 64), 256, 0, stream>>>(x, W1t, h1, 256);
    // fused layer 1->2: z1 = spmm(h1); h2 = tanh(z1 @ W2)   [512 thr, 8 waves]
    fused_spmm_gemm<256, 128, true><<<NNODES / 16, 512, 0, stream>>>(deg, ell, h1, W2t, h2);
    // fused layer 2->3: z2 = spmm(h2); h3 = z2 @ W3         [256 thr, 4 waves]
    fused_spmm_gemm<128, 64, false><<<NNODES / 16, 256, 0, stream>>>(deg, ell, h2, W3t, h3);
    // final spmm: z_igae = spmm(h3) (f32 out + bf16 copy for zzt)
    spmm_final<<<NNODES / 32, 256, 0, stream>>>(deg, ell, h3, Zb, z_igae);
    // adjacency reconstruction
    zzt_sigmoid<<<dim3(NNODES / 256, NNODES / 64), 256, 0, stream>>>((const __bf16*)Zb, adj);
}

// Round 8
// 230.100 us; speedup vs baseline: 1.2098x; 1.0191x over previous
//
#include <hip/hip_runtime.h>
#include <hip/hip_bf16.h>

#define NNODES 12288
#define NEDGES (NNODES * 32)
#define ELLCAP 128  // max degree ~60 (Poisson(32) tail over 12288 rows); 128 unreachable

typedef __attribute__((ext_vector_type(4))) float f32x4;
typedef __attribute__((ext_vector_type(8))) __bf16 bf16x8;

// ---------------- fused prep: zero deg + 3 weight transpose-casts ----------------
__global__ __launch_bounds__(256) void prep_kernel(const float* __restrict__ W1,
                                                   const float* __restrict__ W2,
                                                   const float* __restrict__ W3,
                                                   __bf16* __restrict__ W1t,
                                                   __bf16* __restrict__ W2t,
                                                   __bf16* __restrict__ W3t,
                                                   int* __restrict__ deg) {
    int i = blockIdx.x * 256 + threadIdx.x;
    if (i < NNODES) { deg[i] = 0; return; }
    int j = i - NNODES;
    if (j < 512 * 256) { W1t[(size_t)(j % 256) * 512 + j / 256] = (__bf16)W1[j]; return; }
    j -= 512 * 256;
    if (j < 256 * 128) { W2t[(size_t)(j % 128) * 256 + j / 128] = (__bf16)W2[j]; return; }
    j -= 256 * 128;
    if (j < 128 * 64) { W3t[(size_t)(j % 64) * 128 + j / 64] = (__bf16)W3[j]; return; }
}

// ---------------- merged: gemm1 (blocks 0..383) + ELL scatter (blocks 384..1919) ----
// Both depend only on prep; running them in one dispatch hides the scatter's
// latency-bound atomics under gemm1's MFMA. Kernel boundary then guarantees
// fused12 sees complete h1 AND ell.
__global__ __launch_bounds__(256) void gemm1_scatter(const float* __restrict__ x,
                                                     const __bf16* __restrict__ W1t,
                                                     __bf16* __restrict__ h1,
                                                     const int* __restrict__ erow,
                                                     const int* __restrict__ ecol,
                                                     const float* __restrict__ ew,
                                                     int* __restrict__ deg,
                                                     int2* __restrict__ ell) {
    if (blockIdx.x >= 384) {
        int e = (blockIdx.x - 384) * 256 + threadIdx.x;
        int r = erow[e];
        int p = atomicAdd(&deg[r], 1);
        int2 cw; cw.x = ecol[e]; cw.y = __float_as_int(ew[e]);
        ell[(size_t)r * ELLCAP + p] = cw;
        return;
    }
    // gemm1: h1 = tanh(x @ W1), K=512, Nc=256, f32 A cast in-register.
    // m on (id%96) so the 4 n-blocks sharing an A-panel differ by 96 (%8==0 -> same XCD L2).
    constexpr int K = 512, Nc = 256;
    int wave = threadIdx.x >> 6, lane = threadIdx.x & 63;
    int lr = lane & 15, kg = lane >> 4;
    int m0 = (blockIdx.x % 96) * 128 + wave * 32;
    int n0 = (blockIdx.x / 96) * 64;
    f32x4 acc[2][4];
#pragma unroll
    for (int mi = 0; mi < 2; mi++)
#pragma unroll
        for (int ni = 0; ni < 4; ni++) acc[mi][ni] = (f32x4){0.f, 0.f, 0.f, 0.f};
#pragma unroll
    for (int k0 = 0; k0 < K; k0 += 32) {
        bf16x8 af[2], bf[4];
#pragma unroll
        for (int mi = 0; mi < 2; mi++) {
            const float* ap = x + (size_t)(m0 + mi * 16 + lr) * K + k0 + kg * 8;
            f32x4 a0 = *(const f32x4*)ap;
            f32x4 a1 = *(const f32x4*)(ap + 4);
#pragma unroll
            for (int j = 0; j < 4; j++) { af[mi][j] = (__bf16)a0[j]; af[mi][4 + j] = (__bf16)a1[j]; }
        }
#pragma unroll
        for (int ni = 0; ni < 4; ni++)
            bf[ni] = *(const bf16x8*)(W1t + (size_t)(n0 + ni * 16 + lr) * K + k0 + kg * 8);
#pragma unroll
        for (int mi = 0; mi < 2; mi++)
#pragma unroll
            for (int ni = 0; ni < 4; ni++)
                acc[mi][ni] = __builtin_amdgcn_mfma_f32_16x16x32_bf16(af[mi], bf[ni], acc[mi][ni], 0, 0, 0);
    }
    // C/D layout (m89-verified): col = lane&15, row = (lane>>4)*4 + reg
#pragma unroll
    for (int mi = 0; mi < 2; mi++)
#pragma unroll
        for (int ni = 0; ni < 4; ni++) {
            int col = n0 + ni * 16 + lr;
            int rowb = m0 + mi * 16 + kg * 4;
#pragma unroll
            for (int r = 0; r < 4; r++)
                h1[(size_t)(rowb + r) * Nc + col] = (__bf16)tanhf(acc[mi][ni][r]);
        }
}

// ---------------- fused: z = spmm(h_in) then h_out = act(z @ W) ----------------
template <int K, int NOUT, bool TANH>
__global__ __launch_bounds__(16 * K / 8) void fused_spmm_gemm(const int* __restrict__ deg,
                                                              const int2* __restrict__ ell,
                                                              const __bf16* __restrict__ h_in,
                                                              const __bf16* __restrict__ Wt,
                                                              __bf16* __restrict__ h_out) {
    constexpr int L = K / 8;  // lanes per row in phase A
    __shared__ __bf16 zs[16][K + 4];
    int tid = threadIdx.x;
    int rloc = tid / L;
    int f8 = (tid % L) * 8;
    int rglob = blockIdx.x * 16 + rloc;
    int d = deg[rglob];
    const int2* er = ell + (size_t)rglob * ELLCAP;
    float acc[8] = {};
#pragma unroll 8
    for (int e = 0; e < d; e++) {
        int2 cw = er[e];
        float w = __int_as_float(cw.y);
        bf16x8 hv = *(const bf16x8*)(h_in + (size_t)cw.x * K + f8);
#pragma unroll
        for (int j = 0; j < 8; j++) acc[j] = fmaf(w, (float)hv[j], acc[j]);
    }
    bf16x8 o;
#pragma unroll
    for (int j = 0; j < 8; j++) o[j] = (__bf16)acc[j];
    *(bf16x8*)&zs[rloc][f8] = o;
    __syncthreads();
    // phase B: wave w computes out cols [w*16, w*16+16), rows = block's 16
    int wave = tid >> 6, lane = tid & 63;
    int lr = lane & 15, kg = lane >> 4;
    f32x4 c = (f32x4){0.f, 0.f, 0.f, 0.f};
#pragma unroll
    for (int ks = 0; ks < K / 32; ks++) {
        bf16x8 a = *(const bf16x8*)&zs[lr][ks * 32 + kg * 8];
        bf16x8 b = *(const bf16x8*)(Wt + (size_t)(wave * 16 + lr) * K + ks * 32 + kg * 8);
        c = __builtin_amdgcn_mfma_f32_16x16x32_bf16(a, b, c, 0, 0, 0);
    }
#pragma unroll
    for (int r = 0; r < 4; r++) {
        float v = c[r];
        if (TANH) v = tanhf(v);
        h_out[(size_t)(blockIdx.x * 16 + kg * 4 + r) * NOUT + wave * 16 + lr] = (__bf16)v;
    }
}

// ---------------- final SpMM (F=64): writes Zb bf16 + z_igae f32 ----------------
__global__ __launch_bounds__(256) void spmm_final(const int* __restrict__ deg,
                                                  const int2* __restrict__ ell,
                                                  const __bf16* __restrict__ h,
                                                  __bf16* __restrict__ z,
                                                  float* __restrict__ zf) {
    int r = blockIdx.x * 32 + threadIdx.x / 8;
    int f8 = (threadIdx.x & 7) * 8;
    int d = deg[r];
    const int2* er = ell + (size_t)r * ELLCAP;
    float acc[8] = {};
#pragma unroll 8
    for (int e = 0; e < d; e++) {
        int2 cw = er[e];
        float w = __int_as_float(cw.y);
        bf16x8 hv = *(const bf16x8*)(h + (size_t)cw.x * 64 + f8);
#pragma unroll
        for (int j = 0; j < 8; j++) acc[j] = fmaf(w, (float)hv[j], acc[j]);
    }
    bf16x8 o;
#pragma unroll
    for (int j = 0; j < 8; j++) o[j] = (__bf16)acc[j];
    *(bf16x8*)(z + (size_t)r * 64 + f8) = o;
    f32x4 o0, o1;
#pragma unroll
    for (int j = 0; j < 4; j++) { o0[j] = acc[j]; o1[j] = acc[4 + j]; }
    *(f32x4*)(zf + (size_t)r * 64 + f8) = o0;
    *(f32x4*)(zf + (size_t)r * 64 + f8 + 4) = o1;
}

// ---------------- adj = sigmoid(Z Z^T), LDS double-buffered row-coalesced stores ----
// MFMA identical to r7. Epilogue: 4 phases of 16 rows through 2 LDS buffers
// (same 33.3 KB total footprint -> occupancy unchanged). Between one barrier
// pair, waves store buf[p] (full 1KB rows, fill-kernel pattern ~6.7 TB/s) WHILE
// computing exp/rcp and filling buf[p^1] -> transcendental work overlaps stores.
__global__ __launch_bounds__(256) void zzt_sigmoid(const __bf16* __restrict__ Z,
                                                   float* __restrict__ out) {
    __shared__ float tile[2][16][260];  // 33.3 KB
    int wave = threadIdx.x >> 6;
    int lane = threadIdx.x & 63;
    int lr = lane & 15;
    int kg = lane >> 4;
    int r0 = blockIdx.y * 64;
    int c0blk = blockIdx.x * 256;
    int c0 = c0blk + wave * 64;
    bf16x8 af[4][2], bfr[4][2];
#pragma unroll
    for (int i = 0; i < 4; i++)
#pragma unroll
        for (int ks = 0; ks < 2; ks++) {
            af[i][ks]  = *(const bf16x8*)(Z + (size_t)(r0 + i * 16 + lr) * 64 + ks * 32 + kg * 8);
            bfr[i][ks] = *(const bf16x8*)(Z + (size_t)(c0 + i * 16 + lr) * 64 + ks * 32 + kg * 8);
        }
    f32x4 acc[4][4];
#pragma unroll
    for (int mi = 0; mi < 4; mi++)
#pragma unroll
        for (int ni = 0; ni < 4; ni++) acc[mi][ni] = (f32x4){0.f, 0.f, 0.f, 0.f};
#pragma unroll
    for (int mi = 0; mi < 4; mi++)
#pragma unroll
        for (int ni = 0; ni < 4; ni++) {
            acc[mi][ni] = __builtin_amdgcn_mfma_f32_16x16x32_bf16(af[mi][0], bfr[ni][0], acc[mi][ni], 0, 0, 0);
            acc[mi][ni] = __builtin_amdgcn_mfma_f32_16x16x32_bf16(af[mi][1], bfr[ni][1], acc[mi][ni], 0, 0, 0);
        }
    // fill phase 0 (fragment row mi maps to rows mi*16 + kg*4 + r)
#pragma unroll
    for (int ni = 0; ni < 4; ni++) {
        int colb = wave * 64 + ni * 16 + lr;
#pragma unroll
        for (int r = 0; r < 4; r++) {
            float e = __expf(-acc[0][ni][r]);
            tile[0][kg * 4 + r][colb] = __builtin_amdgcn_rcpf(1.f + e);
        }
    }
    __syncthreads();
#pragma unroll
    for (int p = 0; p < 4; p++) {
        if (p < 3) {  // fill next buffer while this one streams out
#pragma unroll
            for (int ni = 0; ni < 4; ni++) {
                int colb = wave * 64 + ni * 16 + lr;
#pragma unroll
                for (int r = 0; r < 4; r++) {
                    float e = __expf(-acc[p + 1][ni][r]);
                    tile[(p + 1) & 1][kg * 4 + r][colb] = __builtin_amdgcn_rcpf(1.f + e);
                }
            }
        }
        // store buf[p&1]: each wave one full 1KB row per instruction
#pragma unroll
        for (int it = 0; it < 4; it++) {
            int rowl = it * 4 + wave;
            size_t grow = (size_t)(r0 + p * 16 + rowl);
            *(f32x4*)(out + grow * NNODES + c0blk + lane * 4) = *(const f32x4*)&tile[p & 1][rowl][lane * 4];
        }
        __syncthreads();
    }
}

extern "C" void kernel_launch(void* const* d_in, const int* in_sizes, int n_in,
                              void* d_out, int out_size, void* d_ws, size_t ws_size,
                              hipStream_t stream) {
    (void)in_sizes; (void)n_in; (void)out_size; (void)ws_size;
    const float* x  = (const float*)d_in[0];
    const int* erow = (const int*)d_in[1];
    const int* ecol = (const int*)d_in[2];
    const float* ew = (const float*)d_in[3];
    const float* W1 = (const float*)d_in[4];
    const float* W2 = (const float*)d_in[5];
    const float* W3 = (const float*)d_in[6];
    float* z_igae = (float*)d_out;
    float* adj = (float*)d_out + (size_t)NNODES * 64;

    char* ws = (char*)d_ws;
    size_t off = 0;
    auto alloc = [&](size_t bytes) {
        void* p = ws + off;
        off += (bytes + 255) & ~(size_t)255;
        return p;
    };
    __bf16* W1t = (__bf16*)alloc((size_t)512 * 256 * 2);
    __bf16* W2t = (__bf16*)alloc((size_t)256 * 128 * 2);
    __bf16* W3t = (__bf16*)alloc((size_t)128 * 64 * 2);
    __bf16* h1  = (__bf16*)alloc((size_t)NNODES * 256 * 2);
    __bf16* h2  = (__bf16*)alloc((size_t)NNODES * 128 * 2);
    __bf16* h3  = (__bf16*)alloc((size_t)NNODES * 64 * 2);
    __bf16* Zb  = (__bf16*)alloc((size_t)NNODES * 64 * 2);
    int* deg    = (int*)alloc(NNODES * 4);
    int2* ell   = (int2*)alloc((size_t)NNODES * ELLCAP * 8);

    // prep (zero deg + weight casts)
    prep_kernel<<<(NNODES + 512 * 256 + 256 * 128 + 128 * 64 + 255) / 256, 256, 0, stream>>>(
        W1, W2, W3, W1t, W2t, W3t, deg);
    // gemm1 (h1 = tanh(x@W1)) + ELL scatter, concurrently in one dispatch
    gemm1_scatter<<<384 + NEDGES / 256, 256, 0, stream>>>(x, W1t, h1, erow, ecol, ew, deg, ell);
    // fused layer 1->2: z1 = spmm(h1); h2 = tanh(z1 @ W2)   [512 thr, 8 waves]
    fused_spmm_gemm<256, 128, true><<<NNODES / 16, 512, 0, stream>>>(deg, ell, h1, W2t, h2);
    // fused layer 2->3: z2 = spmm(h2); h3 = z2 @ W3         [256 thr, 4 waves]
    fused_spmm_gemm<128, 64, false><<<NNODES / 16, 256, 0, stream>>>(deg, ell, h2, W3t, h3);
    // final spmm: z_igae = spmm(h3) (f32 out + bf16 copy for zzt)
    spmm_final<<<NNODES / 32, 256, 0, stream>>>(deg, ell, h3, Zb, z_igae);
    // adjacency reconstruction
    zzt_sigmoid<<<dim3(NNODES / 256, NNODES / 64), 256, 0, stream>>>((const __bf16*)Zb, adj);
}

// Round 9
// 215.717 us; speedup vs baseline: 1.2905x; 1.0667x over previous
//
#include <hip/hip_runtime.h>
#include <hip/hip_bf16.h>

#define NNODES 12288
#define NEDGES (NNODES * 32)
#define ELLCAP 128  // max degree ~60 (Poisson(32) tail over 12288 rows); 128 unreachable

typedef __attribute__((ext_vector_type(4))) float f32x4;
typedef __attribute__((ext_vector_type(8))) __bf16 bf16x8;

// ---------------- fused prep: zero deg + 3 weight transpose-casts ----------------
__global__ __launch_bounds__(256) void prep_kernel(const float* __restrict__ W1,
                                                   const float* __restrict__ W2,
                                                   const float* __restrict__ W3,
                                                   __bf16* __restrict__ W1t,
                                                   __bf16* __restrict__ W2t,
                                                   __bf16* __restrict__ W3t,
                                                   int* __restrict__ deg) {
    int i = blockIdx.x * 256 + threadIdx.x;
    if (i < NNODES) { deg[i] = 0; return; }
    int j = i - NNODES;
    if (j < 512 * 256) { W1t[(size_t)(j % 256) * 512 + j / 256] = (__bf16)W1[j]; return; }
    j -= 512 * 256;
    if (j < 256 * 128) { W2t[(size_t)(j % 128) * 256 + j / 128] = (__bf16)W2[j]; return; }
    j -= 256 * 128;
    if (j < 128 * 64) { W3t[(size_t)(j % 64) * 128 + j / 64] = (__bf16)W3[j]; return; }
}

// ---------------- merged: gemm1 (blocks 0..383) + ELL scatter (blocks 384..1919) ----
__global__ __launch_bounds__(256) void gemm1_scatter(const float* __restrict__ x,
                                                     const __bf16* __restrict__ W1t,
                                                     __bf16* __restrict__ h1,
                                                     const int* __restrict__ erow,
                                                     const int* __restrict__ ecol,
                                                     const float* __restrict__ ew,
                                                     int* __restrict__ deg,
                                                     int2* __restrict__ ell) {
    if (blockIdx.x >= 384) {
        int e = (blockIdx.x - 384) * 256 + threadIdx.x;
        int r = erow[e];
        int p = atomicAdd(&deg[r], 1);
        int2 cw; cw.x = ecol[e]; cw.y = __float_as_int(ew[e]);
        ell[(size_t)r * ELLCAP + p] = cw;
        return;
    }
    // gemm1: h1 = tanh(x @ W1), K=512, Nc=256, f32 A cast in-register.
    constexpr int K = 512, Nc = 256;
    int wave = threadIdx.x >> 6, lane = threadIdx.x & 63;
    int lr = lane & 15, kg = lane >> 4;
    int m0 = (blockIdx.x % 96) * 128 + wave * 32;
    int n0 = (blockIdx.x / 96) * 64;
    f32x4 acc[2][4];
#pragma unroll
    for (int mi = 0; mi < 2; mi++)
#pragma unroll
        for (int ni = 0; ni < 4; ni++) acc[mi][ni] = (f32x4){0.f, 0.f, 0.f, 0.f};
#pragma unroll
    for (int k0 = 0; k0 < K; k0 += 32) {
        bf16x8 af[2], bf[4];
#pragma unroll
        for (int mi = 0; mi < 2; mi++) {
            const float* ap = x + (size_t)(m0 + mi * 16 + lr) * K + k0 + kg * 8;
            f32x4 a0 = *(const f32x4*)ap;
            f32x4 a1 = *(const f32x4*)(ap + 4);
#pragma unroll
            for (int j = 0; j < 4; j++) { af[mi][j] = (__bf16)a0[j]; af[mi][4 + j] = (__bf16)a1[j]; }
        }
#pragma unroll
        for (int ni = 0; ni < 4; ni++)
            bf[ni] = *(const bf16x8*)(W1t + (size_t)(n0 + ni * 16 + lr) * K + k0 + kg * 8);
#pragma unroll
        for (int mi = 0; mi < 2; mi++)
#pragma unroll
            for (int ni = 0; ni < 4; ni++)
                acc[mi][ni] = __builtin_amdgcn_mfma_f32_16x16x32_bf16(af[mi], bf[ni], acc[mi][ni], 0, 0, 0);
    }
    // C/D layout (m89-verified): col = lane&15, row = (lane>>4)*4 + reg
#pragma unroll
    for (int mi = 0; mi < 2; mi++)
#pragma unroll
        for (int ni = 0; ni < 4; ni++) {
            int col = n0 + ni * 16 + lr;
            int rowb = m0 + mi * 16 + kg * 4;
#pragma unroll
            for (int r = 0; r < 4; r++)
                h1[(size_t)(rowb + r) * Nc + col] = (__bf16)tanhf(acc[mi][ni][r]);
        }
}

// ---------------- generic dense GEMM (for g1 = h1 @ W2): bf16 MFMA ----------------
template <bool TANH, int K>
__global__ __launch_bounds__(256) void gemm_mfma(const __bf16* __restrict__ A,
                                                 const __bf16* __restrict__ Wt,
                                                 __bf16* __restrict__ C, int Nc) {
    int wave = threadIdx.x >> 6, lane = threadIdx.x & 63;
    int lr = lane & 15, kg = lane >> 4;
    int m0 = blockIdx.x * 128 + wave * 32;
    int n0 = blockIdx.y * 64;
    f32x4 acc[2][4];
#pragma unroll
    for (int mi = 0; mi < 2; mi++)
#pragma unroll
        for (int ni = 0; ni < 4; ni++) acc[mi][ni] = (f32x4){0.f, 0.f, 0.f, 0.f};
#pragma unroll
    for (int k0 = 0; k0 < K; k0 += 32) {
        bf16x8 af[2], bf[4];
#pragma unroll
        for (int mi = 0; mi < 2; mi++)
            af[mi] = *(const bf16x8*)(A + (size_t)(m0 + mi * 16 + lr) * K + k0 + kg * 8);
#pragma unroll
        for (int ni = 0; ni < 4; ni++)
            bf[ni] = *(const bf16x8*)(Wt + (size_t)(n0 + ni * 16 + lr) * K + k0 + kg * 8);
#pragma unroll
        for (int mi = 0; mi < 2; mi++)
#pragma unroll
            for (int ni = 0; ni < 4; ni++)
                acc[mi][ni] = __builtin_amdgcn_mfma_f32_16x16x32_bf16(af[mi], bf[ni], acc[mi][ni], 0, 0, 0);
    }
#pragma unroll
    for (int mi = 0; mi < 2; mi++)
#pragma unroll
        for (int ni = 0; ni < 4; ni++) {
            int col = n0 + ni * 16 + lr;
            int rowb = m0 + mi * 16 + kg * 4;
#pragma unroll
            for (int r = 0; r < 4; r++) {
                float v = acc[mi][ni][r];
                if (TANH) v = tanhf(v);
                C[(size_t)(rowb + r) * Nc + col] = (__bf16)v;
            }
        }
}

// ---------------- fusedB: h2 = tanh(spmm_F128(g1)); g2 = h2 @ W3 ----------------
// tanh applied to the SPMM RESULT (before the GEMM), no act after.
__global__ __launch_bounds__(256) void fused_spmm_tanh_gemm(const int* __restrict__ deg,
                                                            const int2* __restrict__ ell,
                                                            const __bf16* __restrict__ g1,
                                                            const __bf16* __restrict__ W3t,
                                                            __bf16* __restrict__ g2) {
    constexpr int K = 128, NOUT = 64, L = K / 8;
    __shared__ __bf16 zs[16][K + 4];
    int tid = threadIdx.x;
    int rloc = tid / L;
    int f8 = (tid % L) * 8;
    int rglob = blockIdx.x * 16 + rloc;
    int d = deg[rglob];
    const int2* er = ell + (size_t)rglob * ELLCAP;
    float acc[8] = {};
#pragma unroll 8
    for (int e = 0; e < d; e++) {
        int2 cw = er[e];
        float w = __int_as_float(cw.y);
        bf16x8 hv = *(const bf16x8*)(g1 + (size_t)cw.x * K + f8);
#pragma unroll
        for (int j = 0; j < 8; j++) acc[j] = fmaf(w, (float)hv[j], acc[j]);
    }
    bf16x8 o;
#pragma unroll
    for (int j = 0; j < 8; j++) o[j] = (__bf16)tanhf(acc[j]);
    *(bf16x8*)&zs[rloc][f8] = o;
    __syncthreads();
    // GEMM: wave w computes out cols [w*16, w*16+16) of g2 for the block's 16 rows
    int wave = tid >> 6, lane = tid & 63;
    int lr = lane & 15, kg = lane >> 4;
    f32x4 c = (f32x4){0.f, 0.f, 0.f, 0.f};
#pragma unroll
    for (int ks = 0; ks < K / 32; ks++) {
        bf16x8 a = *(const bf16x8*)&zs[lr][ks * 32 + kg * 8];
        bf16x8 b = *(const bf16x8*)(W3t + (size_t)(wave * 16 + lr) * K + ks * 32 + kg * 8);
        c = __builtin_amdgcn_mfma_f32_16x16x32_bf16(a, b, c, 0, 0, 0);
    }
#pragma unroll
    for (int r = 0; r < 4; r++)
        g2[(size_t)(blockIdx.x * 16 + kg * 4 + r) * NOUT + wave * 16 + lr] = (__bf16)c[r];
}

// ---------------- SpMM F=64, bf16 out only (t = S . g2) ----------------
__global__ __launch_bounds__(256) void spmm64(const int* __restrict__ deg,
                                              const int2* __restrict__ ell,
                                              const __bf16* __restrict__ h,
                                              __bf16* __restrict__ z) {
    int r = blockIdx.x * 32 + threadIdx.x / 8;
    int f8 = (threadIdx.x & 7) * 8;
    int d = deg[r];
    const int2* er = ell + (size_t)r * ELLCAP;
    float acc[8] = {};
#pragma unroll 8
    for (int e = 0; e < d; e++) {
        int2 cw = er[e];
        float w = __int_as_float(cw.y);
        bf16x8 hv = *(const bf16x8*)(h + (size_t)cw.x * 64 + f8);
#pragma unroll
        for (int j = 0; j < 8; j++) acc[j] = fmaf(w, (float)hv[j], acc[j]);
    }
    bf16x8 o;
#pragma unroll
    for (int j = 0; j < 8; j++) o[j] = (__bf16)acc[j];
    *(bf16x8*)(z + (size_t)r * 64 + f8) = o;
}

// ---------------- final SpMM F=64: z = S . t -> z_igae f32 + Zb bf16 ----------------
__global__ __launch_bounds__(256) void spmm_final(const int* __restrict__ deg,
                                                  const int2* __restrict__ ell,
                                                  const __bf16* __restrict__ h,
                                                  __bf16* __restrict__ z,
                                                  float* __restrict__ zf) {
    int r = blockIdx.x * 32 + threadIdx.x / 8;
    int f8 = (threadIdx.x & 7) * 8;
    int d = deg[r];
    const int2* er = ell + (size_t)r * ELLCAP;
    float acc[8] = {};
#pragma unroll 8
    for (int e = 0; e < d; e++) {
        int2 cw = er[e];
        float w = __int_as_float(cw.y);
        bf16x8 hv = *(const bf16x8*)(h + (size_t)cw.x * 64 + f8);
#pragma unroll
        for (int j = 0; j < 8; j++) acc[j] = fmaf(w, (float)hv[j], acc[j]);
    }
    bf16x8 o;
#pragma unroll
    for (int j = 0; j < 8; j++) o[j] = (__bf16)acc[j];
    *(bf16x8*)(z + (size_t)r * 64 + f8) = o;
    f32x4 o0, o1;
#pragma unroll
    for (int j = 0; j < 4; j++) { o0[j] = acc[j]; o1[j] = acc[4 + j]; }
    *(f32x4*)(zf + (size_t)r * 64 + f8) = o0;
    *(f32x4*)(zf + (size_t)r * 64 + f8 + 4) = o1;
}

// ---------------- adj = sigmoid(Z Z^T), LDS double-buffered row-coalesced stores ----
// (byte-identical to round 8)
__global__ __launch_bounds__(256) void zzt_sigmoid(const __bf16* __restrict__ Z,
                                                   float* __restrict__ out) {
    __shared__ float tile[2][16][260];  // 33.3 KB
    int wave = threadIdx.x >> 6;
    int lane = threadIdx.x & 63;
    int lr = lane & 15;
    int kg = lane >> 4;
    int r0 = blockIdx.y * 64;
    int c0blk = blockIdx.x * 256;
    int c0 = c0blk + wave * 64;
    bf16x8 af[4][2], bfr[4][2];
#pragma unroll
    for (int i = 0; i < 4; i++)
#pragma unroll
        for (int ks = 0; ks < 2; ks++) {
            af[i][ks]  = *(const bf16x8*)(Z + (size_t)(r0 + i * 16 + lr) * 64 + ks * 32 + kg * 8);
            bfr[i][ks] = *(const bf16x8*)(Z + (size_t)(c0 + i * 16 + lr) * 64 + ks * 32 + kg * 8);
        }
    f32x4 acc[4][4];
#pragma unroll
    for (int mi = 0; mi < 4; mi++)
#pragma unroll
        for (int ni = 0; ni < 4; ni++) acc[mi][ni] = (f32x4){0.f, 0.f, 0.f, 0.f};
#pragma unroll
    for (int mi = 0; mi < 4; mi++)
#pragma unroll
        for (int ni = 0; ni < 4; ni++) {
            acc[mi][ni] = __builtin_amdgcn_mfma_f32_16x16x32_bf16(af[mi][0], bfr[ni][0], acc[mi][ni], 0, 0, 0);
            acc[mi][ni] = __builtin_amdgcn_mfma_f32_16x16x32_bf16(af[mi][1], bfr[ni][1], acc[mi][ni], 0, 0, 0);
        }
#pragma unroll
    for (int ni = 0; ni < 4; ni++) {
        int colb = wave * 64 + ni * 16 + lr;
#pragma unroll
        for (int r = 0; r < 4; r++) {
            float e = __expf(-acc[0][ni][r]);
            tile[0][kg * 4 + r][colb] = __builtin_amdgcn_rcpf(1.f + e);
        }
    }
    __syncthreads();
#pragma unroll
    for (int p = 0; p < 4; p++) {
        if (p < 3) {
#pragma unroll
            for (int ni = 0; ni < 4; ni++) {
                int colb = wave * 64 + ni * 16 + lr;
#pragma unroll
                for (int r = 0; r < 4; r++) {
                    float e = __expf(-acc[p + 1][ni][r]);
                    tile[(p + 1) & 1][kg * 4 + r][colb] = __builtin_amdgcn_rcpf(1.f + e);
                }
            }
        }
#pragma unroll
        for (int it = 0; it < 4; it++) {
            int rowl = it * 4 + wave;
            size_t grow = (size_t)(r0 + p * 16 + rowl);
            *(f32x4*)(out + grow * NNODES + c0blk + lane * 4) = *(const f32x4*)&tile[p & 1][rowl][lane * 4];
        }
        __syncthreads();
    }
}

extern "C" void kernel_launch(void* const* d_in, const int* in_sizes, int n_in,
                              void* d_out, int out_size, void* d_ws, size_t ws_size,
                              hipStream_t stream) {
    (void)in_sizes; (void)n_in; (void)out_size; (void)ws_size;
    const float* x  = (const float*)d_in[0];
    const int* erow = (const int*)d_in[1];
    const int* ecol = (const int*)d_in[2];
    const float* ew = (const float*)d_in[3];
    const float* W1 = (const float*)d_in[4];
    const float* W2 = (const float*)d_in[5];
    const float* W3 = (const float*)d_in[6];
    float* z_igae = (float*)d_out;
    float* adj = (float*)d_out + (size_t)NNODES * 64;

    char* ws = (char*)d_ws;
    size_t off = 0;
    auto alloc = [&](size_t bytes) {
        void* p = ws + off;
        off += (bytes + 255) & ~(size_t)255;
        return p;
    };
    __bf16* W1t = (__bf16*)alloc((size_t)512 * 256 * 2);
    __bf16* W2t = (__bf16*)alloc((size_t)256 * 128 * 2);
    __bf16* W3t = (__bf16*)alloc((size_t)128 * 64 * 2);
    __bf16* h1  = (__bf16*)alloc((size_t)NNODES * 256 * 2);
    __bf16* g1  = (__bf16*)alloc((size_t)NNODES * 128 * 2);
    __bf16* g2  = (__bf16*)alloc((size_t)NNODES * 64 * 2);
    __bf16* t   = (__bf16*)alloc((size_t)NNODES * 64 * 2);
    __bf16* Zb  = (__bf16*)alloc((size_t)NNODES * 64 * 2);
    int* deg    = (int*)alloc(NNODES * 4);
    int2* ell   = (int2*)alloc((size_t)NNODES * ELLCAP * 8);

    // prep (zero deg + weight casts)
    prep_kernel<<<(NNODES + 512 * 256 + 256 * 128 + 128 * 64 + 255) / 256, 256, 0, stream>>>(
        W1, W2, W3, W1t, W2t, W3t, deg);
    // h1 = tanh(x@W1) + ELL scatter, concurrently
    gemm1_scatter<<<384 + NEDGES / 256, 256, 0, stream>>>(x, W1t, h1, erow, ecol, ew, deg, ell);
    // g1 = h1 @ W2  (associativity: (S h1) W2 = S (h1 W2))
    gemm_mfma<false, 256><<<dim3(NNODES / 128, 2), 256, 0, stream>>>(h1, W2t, g1, 128);
    // h2 = tanh(S g1); g2 = h2 @ W3  (gather F=128)
    fused_spmm_tanh_gemm<<<NNODES / 16, 256, 0, stream>>>(deg, ell, g1, W3t, g2);
    // t = S g2  (z = S (z2 W3) = S (S g2))
    spmm64<<<NNODES / 32, 256, 0, stream>>>(deg, ell, g2, t);
    // z_igae = S t (f32 + bf16 copy)
    spmm_final<<<NNODES / 32, 256, 0, stream>>>(deg, ell, t, Zb, z_igae);
    // adjacency reconstruction
    zzt_sigmoid<<<dim3(NNODES / 256, NNODES / 64), 256, 0, stream>>>((const __bf16*)Zb, adj);
}